// Round 14
// baseline (290.037 us; speedup 1.0000x reference)
//
#include <hip/hip_runtime.h>
#include <hip/hip_bf16.h>
#include <math.h>

typedef __bf16 bf16x8 __attribute__((ext_vector_type(8)));
typedef float  f32x4  __attribute__((ext_vector_type(4)));

__device__ __forceinline__ unsigned short f2bf(float f) {
    unsigned u = __builtin_bit_cast(unsigned, f);
    unsigned r = u + 0x7FFFu + ((u >> 16) & 1u);
    return (unsigned short)(r >> 16);
}

// fast erf (Abramowitz–Stegun 7.1.26, |err| < 1.5e-7) -> exact-form GELU
__device__ __forceinline__ float gelu_fast(float v) {
    float xs = v * 0.70710678118f;
    float ax = fabsf(xs);
    float t  = __builtin_amdgcn_rcpf(1.0f + 0.3275911f * ax);
    float p  = t * (0.254829592f + t * (-0.284496736f + t * (1.421413741f +
               t * (-1.453152027f + t * 1.061405429f))));
    float er = 1.0f - p * __expf(-ax * ax);
    er = copysignf(er, xs);
    return v * (0.5f + 0.5f * er);
}

__device__ __forceinline__ void gll16(const unsigned short* g, unsigned short* l) {
    __builtin_amdgcn_global_load_lds((const __attribute__((address_space(1))) void*)g,
                                     (__attribute__((address_space(3))) void*)l, 16, 0, 0);
}

// ---------------------------------------------------------------- prep kernels
__global__ void transpose_cast(const float* __restrict__ w, unsigned short* __restrict__ wt,
                               int R, int C) {
    int tid = blockIdx.x * 256 + threadIdx.x;
    if (tid >= R * C) return;
    int c = tid / R, r = tid % R;                  // wt[c][r] = w[r][c]
    wt[(size_t)c * R + r] = f2bf(w[(size_t)r * C + c]);
}

__global__ void relbias_kernel(const float* __restrict__ btab, float* __restrict__ rb) {
    int tid = blockIdx.x * 256 + threadIdx.x;       // 12*64*64
    if (tid >= 12 * 64 * 64) return;
    int h = tid >> 12, ij = tid & 4095, i = ij >> 6, j = ij & 63;
    int iy = i >> 3, ix = i & 7, jy = j >> 3, jx = j & 7;
    int idx = (iy - jy + 7) * 15 + (ix - jx + 7);
    rb[tid] = btab[idx * 12 + h];
}

// ---------------------------------------------------------------- LayerNorm (fp32 in -> bf16 out)
// vectorized: float2 loads (8B/lane), ushort2 stores (4B/lane), all coalesced
__global__ __launch_bounds__(256) void ln_kernel(const float* __restrict__ x,
                                                 const float* __restrict__ w,
                                                 const float* __restrict__ b,
                                                 unsigned short* __restrict__ out) {
    const int lane = threadIdx.x & 63;
    const size_t tok = (size_t)blockIdx.x * 4 + (threadIdx.x >> 6);
    const float* row = x + tok * 384;
    float2 v[3];
    float s = 0.f, s2 = 0.f;
#pragma unroll
    for (int j = 0; j < 3; ++j) {
        v[j] = *(const float2*)(row + lane * 2 + j * 128);
        s  += v[j].x + v[j].y;
        s2 += v[j].x * v[j].x + v[j].y * v[j].y;
    }
#pragma unroll
    for (int m = 1; m < 64; m <<= 1) { s += __shfl_xor(s, m); s2 += __shfl_xor(s2, m); }
    const float mean = s * (1.f / 384.f);
    const float var  = s2 * (1.f / 384.f) - mean * mean;
    const float inv  = rsqrtf(var + 1e-5f);
#pragma unroll
    for (int j = 0; j < 3; ++j) {
        int c = lane * 2 + j * 128;
        ushort2 o;
        o.x = f2bf((v[j].x - mean) * inv * w[c] + b[c]);
        o.y = f2bf((v[j].y - mean) * inv * w[c + 1] + b[c + 1]);
        *(ushort2*)&out[tok * 384 + c] = o;
    }
}

// ---------------------------------------------------------------- GEMM (R9-proven, 512 thr, BMxBN)
// 3 LDS buffers, global_load_lds staged 2 ahead, counted s_waitcnt vmcnt(L)
// + raw s_barrier. PASSED round 9/13 for 512x128 (qkv/proj/fc2) and 256x256.
// EPI 0: bf16=v+bias  1: f32=resid+v+bias  2: bf16=gelu(v+bias)
// EPI 3: bf16=v+bias scattered to [3][12][32768][32]
template <int EPI, int KT, int BM, int BN>
__global__ __launch_bounds__(512, 2) void gemm_b(const unsigned short* __restrict__ A,
                                                 const unsigned short* __restrict__ Bt,
                                                 const float* __restrict__ bias,
                                                 const float* __restrict__ resid,
                                                 void* __restrict__ outp, int N) {
    constexpr int K    = KT * 32;
    constexpr int RA   = BM / 128;
    constexpr int RB   = BN / 128;
    constexpr int L    = RA + RB;
    constexpr int NWN  = BN / 64;
    constexpr int NWM  = 8 / NWN;
    constexpr int WM   = BM / NWM;
    constexpr int MT   = WM / 16;
    constexpr int P    = WM / 32;
    constexpr int BUFB = (BM + BN) * 64;
    __shared__ char smem[3 * BUFB];

    const int t = threadIdx.x, lane = t & 63, w = t >> 6;
    const int wm = w / NWN, wn = w % NWN;
    const int l16 = lane & 15, lk = lane >> 4;

    const int Nt  = N / BN;
    const int cpx = (int)gridDim.x >> 3;
    const int logical = ((int)blockIdx.x & 7) * cpx + ((int)blockIdx.x >> 3);
    const int n0 = (logical % Nt) * BN;
    const int m0 = (logical / Nt) * BM;

    const int srow = t >> 2;          // 0..127
    const int sch  = t & 3;
    const int ssw  = (srow >> 1) & 3;

    const unsigned short* gsrcA[RA];
#pragma unroll
    for (int i = 0; i < RA; ++i)
        gsrcA[i] = A + (size_t)(m0 + i * 128 + srow) * K + (sch ^ ssw) * 8;
    const unsigned short* gsrcB[RB];
#pragma unroll
    for (int j = 0; j < RB; ++j)
        gsrcB[j] = Bt + (size_t)(n0 + j * 128 + srow) * K + (sch ^ ssw) * 8;

    auto stage = [&](int buf, int kk) {
        char* base = smem + buf * BUFB + t * 16;
        const int go = kk * 32;
#pragma unroll
        for (int i = 0; i < RA; ++i)
            gll16(gsrcA[i] + go, (unsigned short*)(base + i * 8192));
#pragma unroll
        for (int j = 0; j < RB; ++j)
            gll16(gsrcB[j] + go, (unsigned short*)(base + BM * 64 + j * 8192));
    };

    f32x4 acc[MT][4] = {};

    stage(0, 0);
    stage(1, 1);

#pragma unroll 3
    for (int kt = 0; kt < KT; ++kt) {
        if (kt + 1 < KT) {
            if constexpr (L == 3)      asm volatile("s_waitcnt vmcnt(3)" ::: "memory");
            else if constexpr (L == 4) asm volatile("s_waitcnt vmcnt(4)" ::: "memory");
            else if constexpr (L == 5) asm volatile("s_waitcnt vmcnt(5)" ::: "memory");
            else                       asm volatile("s_waitcnt vmcnt(6)" ::: "memory");
        } else {
            asm volatile("s_waitcnt vmcnt(0)" ::: "memory");
        }
        asm volatile("s_barrier" ::: "memory");
        if (kt + 2 < KT) stage((kt + 2) % 3, kt + 2);

        const char* sb = smem + (kt % 3) * BUFB;
        bf16x8 af[MT], bf[4];
#pragma unroll
        for (int mt = 0; mt < MT; ++mt) {
            int row = wm * WM + mt * 16 + l16;
            af[mt] = *(const bf16x8*)(sb + row * 64 + ((lk ^ ((row >> 1) & 3)) << 4));
        }
#pragma unroll
        for (int nt = 0; nt < 4; ++nt) {
            int row = wn * 64 + nt * 16 + l16;
            bf[nt] = *(const bf16x8*)(sb + BM * 64 + row * 64 + ((lk ^ ((row >> 1) & 3)) << 4));
        }
#pragma unroll
        for (int mt = 0; mt < MT; ++mt)
#pragma unroll
            for (int nt = 0; nt < 4; ++nt)
                acc[mt][nt] = __builtin_amdgcn_mfma_f32_16x16x32_bf16(
                    af[mt], bf[nt], acc[mt][nt], 0, 0, 0);
    }

    __syncthreads();
    float* eb = (float*)(smem + w * 8192);
    const int colbase = n0 + wn * 64;

#pragma unroll
    for (int p = 0; p < P; ++p) {
#pragma unroll
        for (int mh = 0; mh < 2; ++mh) {
            int mt = p * 2 + mh;
#pragma unroll
            for (int nt = 0; nt < 4; ++nt) {
                int scol = (nt * 16 + l16) ^ (lk << 4);
#pragma unroll
                for (int r = 0; r < 4; ++r) {
                    int lrow = mh * 16 + lk * 4 + r;
                    eb[lrow * 64 + scol] = acc[mt][nt][r];
                }
            }
        }
#pragma unroll
        for (int s = 0; s < 8; ++s) {
            int lrow = s * 4 + (lane >> 4);
            int col  = (lane & 15) * 4;
            f32x4 v = *(const f32x4*)&eb[lrow * 64 + (col ^ (((lrow >> 2) & 3) << 4))];
            int gcol = colbase + col;
            size_t grow = (size_t)(m0 + wm * WM + p * 32 + lrow);
            float4 bv = *(const float4*)&bias[gcol];
            v[0] += bv.x; v[1] += bv.y; v[2] += bv.z; v[3] += bv.w;
            if constexpr (EPI == 0) {
                ushort4 o; o.x = f2bf(v[0]); o.y = f2bf(v[1]); o.z = f2bf(v[2]); o.w = f2bf(v[3]);
                *(ushort4*)&((unsigned short*)outp)[grow * N + gcol] = o;
            } else if constexpr (EPI == 1) {
                float4 rv = *(const float4*)&resid[grow * N + gcol];
                float4 o; o.x = rv.x + v[0]; o.y = rv.y + v[1]; o.z = rv.z + v[2]; o.w = rv.w + v[3];
                *(float4*)&((float*)outp)[grow * N + gcol] = o;
            } else if constexpr (EPI == 2) {
                ushort4 o;
                o.x = f2bf(gelu_fast(v[0]));
                o.y = f2bf(gelu_fast(v[1]));
                o.z = f2bf(gelu_fast(v[2]));
                o.w = f2bf(gelu_fast(v[3]));
                *(ushort4*)&((unsigned short*)outp)[grow * N + gcol] = o;
            } else {
                ushort4 o; o.x = f2bf(v[0]); o.y = f2bf(v[1]); o.z = f2bf(v[2]); o.w = f2bf(v[3]);
                int which = gcol / 384;
                int rem   = gcol - which * 384;
                int head  = rem >> 5, dim = rem & 31;
                size_t addr = ((size_t)(which * 12 + head) * 32768 + grow) * 32 + dim;
                *(ushort4*)&((unsigned short*)outp)[addr] = o;
            }
        }
    }
}

// ---------------------------------------------------------------- windowed attention
// qkv layout: [3][12][32768][32]; grid: 512 windows * 3 head-groups; 4 waves, 1 head/wave
__global__ __launch_bounds__(256) void attn_kernel(const unsigned short* __restrict__ qkv,
                                                   const float* __restrict__ relbias,
                                                   unsigned short* __restrict__ attnout) {
    __shared__ unsigned short sVT[4][2048]; // per-wave V^T 32x64 (swizzled rows of 128B)
    __shared__ unsigned short sP[4][4096];  // per-wave P 64x64 (swizzled); reused for O staging

    const int t    = threadIdx.x;
    const int lane = t & 63;
    const int w    = t >> 6;
    const int l16  = lane & 15, lk = lane >> 4;

    const int wnd = blockIdx.x / 3;
    const int h   = (blockIdx.x % 3) * 4 + w;

    const int b  = wnd >> 6;
    const int wy = (wnd >> 3) & 7;
    const int wx = wnd & 7;
    const int base_tok = b * 4096 + wy * 512 + wx * 8; // + iy*64 + ix

    const unsigned short* Qb = qkv + (size_t)h * (32768 * 32);
    const unsigned short* Kb = qkv + (size_t)(12 + h) * (32768 * 32);
    const unsigned short* Vb = qkv + (size_t)(24 + h) * (32768 * 32);

    bf16x8 qf[4], kf[4];
#pragma unroll
    for (int mt = 0; mt < 4; ++mt) {
        int tok = mt * 16 + l16;
        size_t trow = (size_t)(base_tok + (tok >> 3) * 64 + (tok & 7));
        qf[mt] = *(const bf16x8*)(Qb + trow * 32 + lk * 8);
        kf[mt] = *(const bf16x8*)(Kb + trow * 32 + lk * 8);
    }

    {
        size_t trow = (size_t)(base_tok + (lane >> 3) * 64 + (lane & 7));
        __attribute__((aligned(16))) unsigned short vv[32];
#pragma unroll
        for (int i = 0; i < 4; ++i)
            *(float4*)&vv[i * 8] = *(const float4*)(Vb + trow * 32 + i * 8);
#pragma unroll
        for (int d = 0; d < 32; ++d) {
            int byte = d * 128 + ((lane * 2) ^ ((d & 7) << 4));
            *(unsigned short*)((char*)&sVT[w][0] + byte) = vv[d];
        }
    }

    f32x4 s[4][4] = {};
#pragma unroll
    for (int mt = 0; mt < 4; ++mt)
#pragma unroll
        for (int nt = 0; nt < 4; ++nt)
            s[mt][nt] = __builtin_amdgcn_mfma_f32_16x16x32_bf16(qf[mt], kf[nt], s[mt][nt], 0, 0, 0);

    const float scale = 0.051031036307982884f; // 384^-0.5 (full C, per reference)
#pragma unroll
    for (int mt = 0; mt < 4; ++mt) {
#pragma unroll
        for (int r = 0; r < 4; ++r) {
            int row = mt * 16 + lk * 4 + r;
            float vals[4];
#pragma unroll
            for (int nt = 0; nt < 4; ++nt)
                vals[nt] = s[mt][nt][r] * scale + relbias[((h * 64) + row) * 64 + nt * 16 + l16];
            float mx = fmaxf(fmaxf(vals[0], vals[1]), fmaxf(vals[2], vals[3]));
            mx = fmaxf(mx, __shfl_xor(mx, 1));
            mx = fmaxf(mx, __shfl_xor(mx, 2));
            mx = fmaxf(mx, __shfl_xor(mx, 4));
            mx = fmaxf(mx, __shfl_xor(mx, 8));
            float sum = 0.f;
#pragma unroll
            for (int nt = 0; nt < 4; ++nt) { vals[nt] = __expf(vals[nt] - mx); sum += vals[nt]; }
            sum += __shfl_xor(sum, 1);
            sum += __shfl_xor(sum, 2);
            sum += __shfl_xor(sum, 4);
            sum += __shfl_xor(sum, 8);
            float inv = 1.0f / sum;
#pragma unroll
            for (int nt = 0; nt < 4; ++nt) {
                int col = nt * 16 + l16;
                int byte = row * 128 + ((col * 2) ^ ((row & 7) << 4));
                *(unsigned short*)((char*)&sP[w][0] + byte) = f2bf(vals[nt] * inv);
            }
        }
    }

    f32x4 o[4][2] = {};
#pragma unroll
    for (int kk = 0; kk < 2; ++kk) {
        bf16x8 pf[4], vf[2];
#pragma unroll
        for (int mt = 0; mt < 4; ++mt) {
            int row = mt * 16 + l16;
            int byte = row * 128 + ((kk * 64 + lk * 16) ^ ((row & 7) << 4));
            pf[mt] = *(const bf16x8*)((const char*)&sP[w][0] + byte);
        }
#pragma unroll
        for (int nt = 0; nt < 2; ++nt) {
            int d = nt * 16 + l16;
            int byte = d * 128 + ((kk * 64 + lk * 16) ^ ((d & 7) << 4));
            vf[nt] = *(const bf16x8*)((const char*)&sVT[w][0] + byte);
        }
#pragma unroll
        for (int mt = 0; mt < 4; ++mt)
#pragma unroll
            for (int nt = 0; nt < 2; ++nt)
                o[mt][nt] = __builtin_amdgcn_mfma_f32_16x16x32_bf16(pf[mt], vf[nt], o[mt][nt], 0, 0, 0);
    }

    float* ob = (float*)&sP[w][0];
#pragma unroll
    for (int mt = 0; mt < 4; ++mt)
#pragma unroll
        for (int nt = 0; nt < 2; ++nt) {
            int dim = (nt * 16 + l16) ^ ((lk & 1) << 4);
#pragma unroll
            for (int r = 0; r < 4; ++r) {
                int tok = mt * 16 + lk * 4 + r;
                ob[tok * 32 + dim] = o[mt][nt][r];
            }
        }
#pragma unroll
    for (int s2 = 0; s2 < 8; ++s2) {
        int tok = s2 * 8 + (lane >> 3);
        int dim = (lane & 7) * 4;
        f32x4 v = *(const f32x4*)&ob[tok * 32 + (dim ^ (((tok >> 2) & 1) << 4))];
        size_t orow = (size_t)(base_tok + (tok >> 3) * 64 + (tok & 7)) * 384 + h * 32 + dim;
        ushort4 ov; ov.x = f2bf(v[0]); ov.y = f2bf(v[1]); ov.z = f2bf(v[2]); ov.w = f2bf(v[3]);
        *(ushort4*)&attnout[orow] = ov;
    }
}

// ---------------------------------------------------------------- launch
extern "C" void kernel_launch(void* const* d_in, const int* in_sizes, int n_in,
                              void* d_out, int out_size, void* d_ws, size_t ws_size,
                              hipStream_t stream) {
    (void)in_sizes; (void)n_in; (void)out_size; (void)ws_size;
    const float* x      = (const float*)d_in[0];
    const float* ln1_w  = (const float*)d_in[1];
    const float* ln1_b  = (const float*)d_in[2];
    const float* qkv_w  = (const float*)d_in[3];
    const float* qkv_b  = (const float*)d_in[4];
    const float* btab   = (const float*)d_in[5];
    const float* proj_w = (const float*)d_in[6];
    const float* proj_b = (const float*)d_in[7];
    const float* ln2_w  = (const float*)d_in[8];
    const float* ln2_b  = (const float*)d_in[9];
    const float* fc1_w  = (const float*)d_in[10];
    const float* fc1_b  = (const float*)d_in[11];
    const float* fc2_w  = (const float*)d_in[12];
    const float* fc2_b  = (const float*)d_in[13];

    char* p = (char*)d_ws;
    auto alloc = [&](size_t bytes) {
        char* r = p;
        p += (bytes + 255) & ~(size_t)255;
        return r;
    };
    unsigned short* wqkv_t  = (unsigned short*)alloc((size_t)1152 * 384 * 2);
    unsigned short* wproj_t = (unsigned short*)alloc((size_t)384 * 384 * 2);
    unsigned short* wfc1_t  = (unsigned short*)alloc((size_t)1536 * 384 * 2);
    unsigned short* wfc2_t  = (unsigned short*)alloc((size_t)384 * 1536 * 2);
    float*          relbias = (float*)alloc((size_t)12 * 64 * 64 * 4);
    unsigned short* hbuf    = (unsigned short*)alloc((size_t)32768 * 384 * 2);
    unsigned short* bigbuf  = (unsigned short*)alloc((size_t)32768 * 1536 * 2); // qkv-perm, then fc1out
    unsigned short* attno   = (unsigned short*)alloc((size_t)32768 * 384 * 2);
    float*          x2      = (float*)alloc((size_t)32768 * 384 * 4);

    const int T = 32768;

    transpose_cast<<<(384 * 1152 + 255) / 256, 256, 0, stream>>>(qkv_w, wqkv_t, 384, 1152);
    transpose_cast<<<(384 * 384 + 255) / 256, 256, 0, stream>>>(proj_w, wproj_t, 384, 384);
    transpose_cast<<<(384 * 1536 + 255) / 256, 256, 0, stream>>>(fc1_w, wfc1_t, 384, 1536);
    transpose_cast<<<(1536 * 384 + 255) / 256, 256, 0, stream>>>(fc2_w, wfc2_t, 1536, 384);
    relbias_kernel<<<(12 * 64 * 64 + 255) / 256, 256, 0, stream>>>(btab, relbias);

    ln_kernel<<<T / 4, 256, 0, stream>>>(x, ln1_w, ln1_b, hbuf);
    // qkv: 512x128 -> grid 9 * 64 = 576
    gemm_b<3, 12, 512, 128><<<(1152 / 128) * (T / 512), 512, 0, stream>>>(
        hbuf, wqkv_t, qkv_b, nullptr, bigbuf, 1152);
    attn_kernel<<<512 * 3, 256, 0, stream>>>(bigbuf, relbias, attno);
    // proj: 512x128 -> grid 3 * 64 = 192
    gemm_b<1, 12, 512, 128><<<(384 / 128) * (T / 512), 512, 0, stream>>>(
        attno, wproj_t, proj_b, x, x2, 384);
    ln_kernel<<<T / 4, 256, 0, stream>>>(x2, ln2_w, ln2_b, hbuf);
    // fc1: 512x128 (was 128x128 gemm_a / 256x256 — both slower per ingress law)
    //   grid 12 * 64 = 768; staged 369 MB at ~2 blocks/CU ingress
    gemm_b<2, 12, 512, 128><<<(1536 / 128) * (T / 512), 512, 0, stream>>>(
        hbuf, wfc1_t, fc1_b, nullptr, bigbuf, 1536);
    // fc2: 512x128, KT=48 -> grid 3 * 64 = 192
    gemm_b<1, 48, 512, 128><<<(384 / 128) * (T / 512), 512, 0, stream>>>(
        bigbuf, wfc2_t, fc2_b, x2, (float*)d_out, 384);
}

// Round 15
// 262.363 us; speedup vs baseline: 1.1055x; 1.1055x over previous
//
#include <hip/hip_runtime.h>
#include <hip/hip_bf16.h>
#include <math.h>

typedef __bf16 bf16x8 __attribute__((ext_vector_type(8)));
typedef float  f32x4  __attribute__((ext_vector_type(4)));

__device__ __forceinline__ unsigned short f2bf(float f) {
    unsigned u = __builtin_bit_cast(unsigned, f);
    unsigned r = u + 0x7FFFu + ((u >> 16) & 1u);
    return (unsigned short)(r >> 16);
}
__device__ __forceinline__ float bf2f(unsigned short s) {
    unsigned u = (unsigned)s << 16;
    return __builtin_bit_cast(float, u);
}

// fast erf (Abramowitz–Stegun 7.1.26, |err| < 1.5e-7) -> exact-form GELU
__device__ __forceinline__ float gelu_fast(float v) {
    float xs = v * 0.70710678118f;
    float ax = fabsf(xs);
    float t  = __builtin_amdgcn_rcpf(1.0f + 0.3275911f * ax);
    float p  = t * (0.254829592f + t * (-0.284496736f + t * (1.421413741f +
               t * (-1.453152027f + t * 1.061405429f))));
    float er = 1.0f - p * __expf(-ax * ax);
    er = copysignf(er, xs);
    return v * (0.5f + 0.5f * er);
}

__device__ __forceinline__ void gll16(const unsigned short* g, unsigned short* l) {
    __builtin_amdgcn_global_load_lds((const __attribute__((address_space(1))) void*)g,
                                     (__attribute__((address_space(3))) void*)l, 16, 0, 0);
}

// ---------------------------------------------------------------- prep kernels
__global__ void transpose_cast(const float* __restrict__ w, unsigned short* __restrict__ wt,
                               int R, int C) {
    int tid = blockIdx.x * 256 + threadIdx.x;
    if (tid >= R * C) return;
    int c = tid / R, r = tid % R;                  // wt[c][r] = w[r][c]
    wt[(size_t)c * R + r] = f2bf(w[(size_t)r * C + c]);
}

__global__ void relbias_kernel(const float* __restrict__ btab, float* __restrict__ rb) {
    int tid = blockIdx.x * 256 + threadIdx.x;       // 12*64*64
    if (tid >= 12 * 64 * 64) return;
    int h = tid >> 12, ij = tid & 4095, i = ij >> 6, j = ij & 63;
    int iy = i >> 3, ix = i & 7, jy = j >> 3, jx = j & 7;
    int idx = (iy - jy + 7) * 15 + (ix - jx + 7);
    rb[tid] = btab[idx * 12 + h];
}

// ---------------------------------------------------------------- LayerNorm (fp32 in -> bf16 out)
__global__ __launch_bounds__(256) void ln_kernel(const float* __restrict__ x,
                                                 const float* __restrict__ w,
                                                 const float* __restrict__ b,
                                                 unsigned short* __restrict__ out) {
    const int lane = threadIdx.x & 63;
    const size_t tok = (size_t)blockIdx.x * 4 + (threadIdx.x >> 6);
    const float* row = x + tok * 384;
    float2 v[3];
    float s = 0.f, s2 = 0.f;
#pragma unroll
    for (int j = 0; j < 3; ++j) {
        v[j] = *(const float2*)(row + lane * 2 + j * 128);
        s  += v[j].x + v[j].y;
        s2 += v[j].x * v[j].x + v[j].y * v[j].y;
    }
#pragma unroll
    for (int m = 1; m < 64; m <<= 1) { s += __shfl_xor(s, m); s2 += __shfl_xor(s2, m); }
    const float mean = s * (1.f / 384.f);
    const float var  = s2 * (1.f / 384.f) - mean * mean;
    const float inv  = rsqrtf(var + 1e-5f);
#pragma unroll
    for (int j = 0; j < 3; ++j) {
        int c = lane * 2 + j * 128;
        ushort2 o;
        o.x = f2bf((v[j].x - mean) * inv * w[c] + b[c]);
        o.y = f2bf((v[j].y - mean) * inv * w[c + 1] + b[c + 1]);
        *(ushort2*)&out[tok * 384 + c] = o;
    }
}

// ---------------------------------------------------------------- LayerNorm (bf16 in -> bf16 out)
__global__ __launch_bounds__(256) void ln_kernel_bf16(const unsigned short* __restrict__ x,
                                                      const float* __restrict__ w,
                                                      const float* __restrict__ b,
                                                      unsigned short* __restrict__ out) {
    const int lane = threadIdx.x & 63;
    const size_t tok = (size_t)blockIdx.x * 4 + (threadIdx.x >> 6);
    const unsigned short* row = x + tok * 384;
    float v[6];
    float s = 0.f, s2 = 0.f;
#pragma unroll
    for (int j = 0; j < 3; ++j) {
        ushort2 u = *(const ushort2*)(row + lane * 2 + j * 128);
        v[j * 2]     = bf2f(u.x);
        v[j * 2 + 1] = bf2f(u.y);
        s  += v[j * 2] + v[j * 2 + 1];
        s2 += v[j * 2] * v[j * 2] + v[j * 2 + 1] * v[j * 2 + 1];
    }
#pragma unroll
    for (int m = 1; m < 64; m <<= 1) { s += __shfl_xor(s, m); s2 += __shfl_xor(s2, m); }
    const float mean = s * (1.f / 384.f);
    const float var  = s2 * (1.f / 384.f) - mean * mean;
    const float inv  = rsqrtf(var + 1e-5f);
#pragma unroll
    for (int j = 0; j < 3; ++j) {
        int c = lane * 2 + j * 128;
        ushort2 o;
        o.x = f2bf((v[j * 2]     - mean) * inv * w[c] + b[c]);
        o.y = f2bf((v[j * 2 + 1] - mean) * inv * w[c + 1] + b[c + 1]);
        *(ushort2*)&out[tok * 384 + c] = o;
    }
}

// ---------------------------------------------------------------- GEMM (R9-proven, 512 thr, BMxBN)
// 3 LDS buffers, global_load_lds staged 2 ahead, counted s_waitcnt vmcnt(L)
// + raw s_barrier. PASSED rounds 9/13/14 for 512x128 and 256x256.
// EPI 0: bf16=v+bias             1: f32 = f32resid + v + bias
// EPI 2: bf16=gelu(v+bias)       3: bf16=v+bias scattered to [3][12][32768][32]
// EPI 4: bf16 = f32resid + v + bias   5: f32 = bf16resid + v + bias
template <int EPI, int KT, int BM, int BN>
__global__ __launch_bounds__(512, 2) void gemm_b(const unsigned short* __restrict__ A,
                                                 const unsigned short* __restrict__ Bt,
                                                 const float* __restrict__ bias,
                                                 const void* __restrict__ resid,
                                                 void* __restrict__ outp, int N) {
    constexpr int K    = KT * 32;
    constexpr int RA   = BM / 128;
    constexpr int RB   = BN / 128;
    constexpr int L    = RA + RB;
    constexpr int NWN  = BN / 64;
    constexpr int NWM  = 8 / NWN;
    constexpr int WM   = BM / NWM;
    constexpr int MT   = WM / 16;
    constexpr int P    = WM / 32;
    constexpr int BUFB = (BM + BN) * 64;
    __shared__ char smem[3 * BUFB];

    const int t = threadIdx.x, lane = t & 63, w = t >> 6;
    const int wm = w / NWN, wn = w % NWN;
    const int l16 = lane & 15, lk = lane >> 4;

    const int Nt  = N / BN;
    const int cpx = (int)gridDim.x >> 3;
    const int logical = ((int)blockIdx.x & 7) * cpx + ((int)blockIdx.x >> 3);
    const int n0 = (logical % Nt) * BN;
    const int m0 = (logical / Nt) * BM;

    const int srow = t >> 2;          // 0..127
    const int sch  = t & 3;
    const int ssw  = (srow >> 1) & 3;

    const unsigned short* gsrcA[RA];
#pragma unroll
    for (int i = 0; i < RA; ++i)
        gsrcA[i] = A + (size_t)(m0 + i * 128 + srow) * K + (sch ^ ssw) * 8;
    const unsigned short* gsrcB[RB];
#pragma unroll
    for (int j = 0; j < RB; ++j)
        gsrcB[j] = Bt + (size_t)(n0 + j * 128 + srow) * K + (sch ^ ssw) * 8;

    auto stage = [&](int buf, int kk) {
        char* base = smem + buf * BUFB + t * 16;
        const int go = kk * 32;
#pragma unroll
        for (int i = 0; i < RA; ++i)
            gll16(gsrcA[i] + go, (unsigned short*)(base + i * 8192));
#pragma unroll
        for (int j = 0; j < RB; ++j)
            gll16(gsrcB[j] + go, (unsigned short*)(base + BM * 64 + j * 8192));
    };

    f32x4 acc[MT][4] = {};

    stage(0, 0);
    stage(1, 1);

#pragma unroll 3
    for (int kt = 0; kt < KT; ++kt) {
        if (kt + 1 < KT) {
            if constexpr (L == 3)      asm volatile("s_waitcnt vmcnt(3)" ::: "memory");
            else if constexpr (L == 4) asm volatile("s_waitcnt vmcnt(4)" ::: "memory");
            else if constexpr (L == 5) asm volatile("s_waitcnt vmcnt(5)" ::: "memory");
            else                       asm volatile("s_waitcnt vmcnt(6)" ::: "memory");
        } else {
            asm volatile("s_waitcnt vmcnt(0)" ::: "memory");
        }
        asm volatile("s_barrier" ::: "memory");
        if (kt + 2 < KT) stage((kt + 2) % 3, kt + 2);

        const char* sb = smem + (kt % 3) * BUFB;
        bf16x8 af[MT], bf[4];
#pragma unroll
        for (int mt = 0; mt < MT; ++mt) {
            int row = wm * WM + mt * 16 + l16;
            af[mt] = *(const bf16x8*)(sb + row * 64 + ((lk ^ ((row >> 1) & 3)) << 4));
        }
#pragma unroll
        for (int nt = 0; nt < 4; ++nt) {
            int row = wn * 64 + nt * 16 + l16;
            bf[nt] = *(const bf16x8*)(sb + BM * 64 + row * 64 + ((lk ^ ((row >> 1) & 3)) << 4));
        }
#pragma unroll
        for (int mt = 0; mt < MT; ++mt)
#pragma unroll
            for (int nt = 0; nt < 4; ++nt)
                acc[mt][nt] = __builtin_amdgcn_mfma_f32_16x16x32_bf16(
                    af[mt], bf[nt], acc[mt][nt], 0, 0, 0);
    }

    __syncthreads();
    float* eb = (float*)(smem + w * 8192);
    const int colbase = n0 + wn * 64;

#pragma unroll
    for (int p = 0; p < P; ++p) {
#pragma unroll
        for (int mh = 0; mh < 2; ++mh) {
            int mt = p * 2 + mh;
#pragma unroll
            for (int nt = 0; nt < 4; ++nt) {
                int scol = (nt * 16 + l16) ^ (lk << 4);
#pragma unroll
                for (int r = 0; r < 4; ++r) {
                    int lrow = mh * 16 + lk * 4 + r;
                    eb[lrow * 64 + scol] = acc[mt][nt][r];
                }
            }
        }
#pragma unroll
        for (int s = 0; s < 8; ++s) {
            int lrow = s * 4 + (lane >> 4);
            int col  = (lane & 15) * 4;
            f32x4 v = *(const f32x4*)&eb[lrow * 64 + (col ^ (((lrow >> 2) & 3) << 4))];
            int gcol = colbase + col;
            size_t grow = (size_t)(m0 + wm * WM + p * 32 + lrow);
            float4 bv = *(const float4*)&bias[gcol];
            v[0] += bv.x; v[1] += bv.y; v[2] += bv.z; v[3] += bv.w;
            if constexpr (EPI == 0) {
                ushort4 o; o.x = f2bf(v[0]); o.y = f2bf(v[1]); o.z = f2bf(v[2]); o.w = f2bf(v[3]);
                *(ushort4*)&((unsigned short*)outp)[grow * N + gcol] = o;
            } else if constexpr (EPI == 1) {
                float4 rv = *(const float4*)&((const float*)resid)[grow * N + gcol];
                float4 o; o.x = rv.x + v[0]; o.y = rv.y + v[1]; o.z = rv.z + v[2]; o.w = rv.w + v[3];
                *(float4*)&((float*)outp)[grow * N + gcol] = o;
            } else if constexpr (EPI == 2) {
                ushort4 o;
                o.x = f2bf(gelu_fast(v[0]));
                o.y = f2bf(gelu_fast(v[1]));
                o.z = f2bf(gelu_fast(v[2]));
                o.w = f2bf(gelu_fast(v[3]));
                *(ushort4*)&((unsigned short*)outp)[grow * N + gcol] = o;
            } else if constexpr (EPI == 3) {
                ushort4 o; o.x = f2bf(v[0]); o.y = f2bf(v[1]); o.z = f2bf(v[2]); o.w = f2bf(v[3]);
                int which = gcol / 384;
                int rem   = gcol - which * 384;
                int head  = rem >> 5, dim = rem & 31;
                size_t addr = ((size_t)(which * 12 + head) * 32768 + grow) * 32 + dim;
                *(ushort4*)&((unsigned short*)outp)[addr] = o;
            } else if constexpr (EPI == 4) {
                // bf16 out = f32 resid + v + bias (x2 intermediate in bf16)
                float4 rv = *(const float4*)&((const float*)resid)[grow * N + gcol];
                ushort4 o;
                o.x = f2bf(rv.x + v[0]); o.y = f2bf(rv.y + v[1]);
                o.z = f2bf(rv.z + v[2]); o.w = f2bf(rv.w + v[3]);
                *(ushort4*)&((unsigned short*)outp)[grow * N + gcol] = o;
            } else {
                // EPI 5: f32 out = bf16 resid + v + bias (final output)
                ushort4 rv = *(const ushort4*)&((const unsigned short*)resid)[grow * N + gcol];
                float4 o;
                o.x = bf2f(rv.x) + v[0]; o.y = bf2f(rv.y) + v[1];
                o.z = bf2f(rv.z) + v[2]; o.w = bf2f(rv.w) + v[3];
                *(float4*)&((float*)outp)[grow * N + gcol] = o;
            }
        }
    }
}

// ---------------------------------------------------------------- windowed attention
// qkv layout: [3][12][32768][32]; grid: 512 windows * 3 head-groups; 4 waves, 1 head/wave
__global__ __launch_bounds__(256) void attn_kernel(const unsigned short* __restrict__ qkv,
                                                   const float* __restrict__ relbias,
                                                   unsigned short* __restrict__ attnout) {
    __shared__ unsigned short sVT[4][2048]; // per-wave V^T 32x64 (swizzled rows of 128B)
    __shared__ unsigned short sP[4][4096];  // per-wave P 64x64 (swizzled); reused for O staging

    const int t    = threadIdx.x;
    const int lane = t & 63;
    const int w    = t >> 6;
    const int l16  = lane & 15, lk = lane >> 4;

    const int wnd = blockIdx.x / 3;
    const int h   = (blockIdx.x % 3) * 4 + w;

    const int b  = wnd >> 6;
    const int wy = (wnd >> 3) & 7;
    const int wx = wnd & 7;
    const int base_tok = b * 4096 + wy * 512 + wx * 8; // + iy*64 + ix

    const unsigned short* Qb = qkv + (size_t)h * (32768 * 32);
    const unsigned short* Kb = qkv + (size_t)(12 + h) * (32768 * 32);
    const unsigned short* Vb = qkv + (size_t)(24 + h) * (32768 * 32);

    bf16x8 qf[4], kf[4];
#pragma unroll
    for (int mt = 0; mt < 4; ++mt) {
        int tok = mt * 16 + l16;
        size_t trow = (size_t)(base_tok + (tok >> 3) * 64 + (tok & 7));
        qf[mt] = *(const bf16x8*)(Qb + trow * 32 + lk * 8);
        kf[mt] = *(const bf16x8*)(Kb + trow * 32 + lk * 8);
    }

    {
        size_t trow = (size_t)(base_tok + (lane >> 3) * 64 + (lane & 7));
        __attribute__((aligned(16))) unsigned short vv[32];
#pragma unroll
        for (int i = 0; i < 4; ++i)
            *(float4*)&vv[i * 8] = *(const float4*)(Vb + trow * 32 + i * 8);
#pragma unroll
        for (int d = 0; d < 32; ++d) {
            int byte = d * 128 + ((lane * 2) ^ ((d & 7) << 4));
            *(unsigned short*)((char*)&sVT[w][0] + byte) = vv[d];
        }
    }

    f32x4 s[4][4] = {};
#pragma unroll
    for (int mt = 0; mt < 4; ++mt)
#pragma unroll
        for (int nt = 0; nt < 4; ++nt)
            s[mt][nt] = __builtin_amdgcn_mfma_f32_16x16x32_bf16(qf[mt], kf[nt], s[mt][nt], 0, 0, 0);

    const float scale = 0.051031036307982884f; // 384^-0.5 (full C, per reference)
#pragma unroll
    for (int mt = 0; mt < 4; ++mt) {
#pragma unroll
        for (int r = 0; r < 4; ++r) {
            int row = mt * 16 + lk * 4 + r;
            float vals[4];
#pragma unroll
            for (int nt = 0; nt < 4; ++nt)
                vals[nt] = s[mt][nt][r] * scale + relbias[((h * 64) + row) * 64 + nt * 16 + l16];
            float mx = fmaxf(fmaxf(vals[0], vals[1]), fmaxf(vals[2], vals[3]));
            mx = fmaxf(mx, __shfl_xor(mx, 1));
            mx = fmaxf(mx, __shfl_xor(mx, 2));
            mx = fmaxf(mx, __shfl_xor(mx, 4));
            mx = fmaxf(mx, __shfl_xor(mx, 8));
            float sum = 0.f;
#pragma unroll
            for (int nt = 0; nt < 4; ++nt) { vals[nt] = __expf(vals[nt] - mx); sum += vals[nt]; }
            sum += __shfl_xor(sum, 1);
            sum += __shfl_xor(sum, 2);
            sum += __shfl_xor(sum, 4);
            sum += __shfl_xor(sum, 8);
            float inv = 1.0f / sum;
#pragma unroll
            for (int nt = 0; nt < 4; ++nt) {
                int col = nt * 16 + l16;
                int byte = row * 128 + ((col * 2) ^ ((row & 7) << 4));
                *(unsigned short*)((char*)&sP[w][0] + byte) = f2bf(vals[nt] * inv);
            }
        }
    }

    f32x4 o[4][2] = {};
#pragma unroll
    for (int kk = 0; kk < 2; ++kk) {
        bf16x8 pf[4], vf[2];
#pragma unroll
        for (int mt = 0; mt < 4; ++mt) {
            int row = mt * 16 + l16;
            int byte = row * 128 + ((kk * 64 + lk * 16) ^ ((row & 7) << 4));
            pf[mt] = *(const bf16x8*)((const char*)&sP[w][0] + byte);
        }
#pragma unroll
        for (int nt = 0; nt < 2; ++nt) {
            int d = nt * 16 + l16;
            int byte = d * 128 + ((kk * 64 + lk * 16) ^ ((d & 7) << 4));
            vf[nt] = *(const bf16x8*)((const char*)&sVT[w][0] + byte);
        }
#pragma unroll
        for (int mt = 0; mt < 4; ++mt)
#pragma unroll
            for (int nt = 0; nt < 2; ++nt)
                o[mt][nt] = __builtin_amdgcn_mfma_f32_16x16x32_bf16(pf[mt], vf[nt], o[mt][nt], 0, 0, 0);
    }

    float* ob = (float*)&sP[w][0];
#pragma unroll
    for (int mt = 0; mt < 4; ++mt)
#pragma unroll
        for (int nt = 0; nt < 2; ++nt) {
            int dim = (nt * 16 + l16) ^ ((lk & 1) << 4);
#pragma unroll
            for (int r = 0; r < 4; ++r) {
                int tok = mt * 16 + lk * 4 + r;
                ob[tok * 32 + dim] = o[mt][nt][r];
            }
        }
#pragma unroll
    for (int s2 = 0; s2 < 8; ++s2) {
        int tok = s2 * 8 + (lane >> 3);
        int dim = (lane & 7) * 4;
        f32x4 v = *(const f32x4*)&ob[tok * 32 + (dim ^ (((tok >> 2) & 1) << 4))];
        size_t orow = (size_t)(base_tok + (tok >> 3) * 64 + (tok & 7)) * 384 + h * 32 + dim;
        ushort4 ov; ov.x = f2bf(v[0]); ov.y = f2bf(v[1]); ov.z = f2bf(v[2]); ov.w = f2bf(v[3]);
        *(ushort4*)&attnout[orow] = ov;
    }
}

// ---------------------------------------------------------------- launch
extern "C" void kernel_launch(void* const* d_in, const int* in_sizes, int n_in,
                              void* d_out, int out_size, void* d_ws, size_t ws_size,
                              hipStream_t stream) {
    (void)in_sizes; (void)n_in; (void)out_size; (void)ws_size;
    const float* x      = (const float*)d_in[0];
    const float* ln1_w  = (const float*)d_in[1];
    const float* ln1_b  = (const float*)d_in[2];
    const float* qkv_w  = (const float*)d_in[3];
    const float* qkv_b  = (const float*)d_in[4];
    const float* btab   = (const float*)d_in[5];
    const float* proj_w = (const float*)d_in[6];
    const float* proj_b = (const float*)d_in[7];
    const float* ln2_w  = (const float*)d_in[8];
    const float* ln2_b  = (const float*)d_in[9];
    const float* fc1_w  = (const float*)d_in[10];
    const float* fc1_b  = (const float*)d_in[11];
    const float* fc2_w  = (const float*)d_in[12];
    const float* fc2_b  = (const float*)d_in[13];

    char* p = (char*)d_ws;
    auto alloc = [&](size_t bytes) {
        char* r = p;
        p += (bytes + 255) & ~(size_t)255;
        return r;
    };
    unsigned short* wqkv_t  = (unsigned short*)alloc((size_t)1152 * 384 * 2);
    unsigned short* wproj_t = (unsigned short*)alloc((size_t)384 * 384 * 2);
    unsigned short* wfc1_t  = (unsigned short*)alloc((size_t)1536 * 384 * 2);
    unsigned short* wfc2_t  = (unsigned short*)alloc((size_t)384 * 1536 * 2);
    float*          relbias = (float*)alloc((size_t)12 * 64 * 64 * 4);
    unsigned short* hbuf    = (unsigned short*)alloc((size_t)32768 * 384 * 2);
    unsigned short* bigbuf  = (unsigned short*)alloc((size_t)32768 * 1536 * 2); // qkv-perm, then fc1out
    unsigned short* attno   = (unsigned short*)alloc((size_t)32768 * 384 * 2);
    unsigned short* x2b     = (unsigned short*)alloc((size_t)32768 * 384 * 2);  // bf16 x2

    const int T = 32768;

    transpose_cast<<<(384 * 1152 + 255) / 256, 256, 0, stream>>>(qkv_w, wqkv_t, 384, 1152);
    transpose_cast<<<(384 * 384 + 255) / 256, 256, 0, stream>>>(proj_w, wproj_t, 384, 384);
    transpose_cast<<<(384 * 1536 + 255) / 256, 256, 0, stream>>>(fc1_w, wfc1_t, 384, 1536);
    transpose_cast<<<(1536 * 384 + 255) / 256, 256, 0, stream>>>(fc2_w, wfc2_t, 1536, 384);
    relbias_kernel<<<(12 * 64 * 64 + 255) / 256, 256, 0, stream>>>(btab, relbias);

    ln_kernel<<<T / 4, 256, 0, stream>>>(x, ln1_w, ln1_b, hbuf);
    // qkv: 512x128 -> grid 9 * 64 = 576
    gemm_b<3, 12, 512, 128><<<(1152 / 128) * (T / 512), 512, 0, stream>>>(
        hbuf, wqkv_t, qkv_b, nullptr, bigbuf, 1152);
    attn_kernel<<<512 * 3, 256, 0, stream>>>(bigbuf, relbias, attno);
    // proj: 512x128, EPI=4 (bf16 x2 = f32 x + v + bias) -> grid 3 * 64 = 192
    gemm_b<4, 12, 512, 128><<<(384 / 128) * (T / 512), 512, 0, stream>>>(
        attno, wproj_t, proj_b, x, x2b, 384);
    ln_kernel_bf16<<<T / 4, 256, 0, stream>>>(x2b, ln2_w, ln2_b, hbuf);
    // fc1: 256x256 (R9-best-total config) -> grid 6 * 128 = 768
    gemm_b<2, 12, 256, 256><<<(1536 / 256) * (T / 256), 512, 0, stream>>>(
        hbuf, wfc1_t, fc1_b, nullptr, bigbuf, 1536);
    // fc2: 512x128, KT=48, EPI=5 (f32 out = bf16 x2 + v + bias) -> grid 3 * 64 = 192
    gemm_b<5, 48, 512, 128><<<(384 / 128) * (T / 512), 512, 0, stream>>>(
        bigbuf, wfc2_t, fc2_b, x2b, (float*)d_out, 384);
}